// Round 15
// baseline (258.146 us; speedup 1.0000x reference)
//
#include <hip/hip_runtime.h>

// 2-layer LSTM, B=1024 T=512 D=1 H=64. 256 blocks x 512 threads (8 waves), MB=4.
// R14 (role-split, lag-2 pipeline, 1 barrier/interval, batch=quad row-dup,
// gate=acc[g][0], zero shuffles) + R15 PRE-ACCUMULATION: L1's h0(s)-part
// product is computed one interval EARLY (h0(s) is in LDS 2 intervals before
// use): 8 h0-part MFMAs run in the previous interval's VALU-tail window where
// the matrix pipe is idle. Post-barrier window now has only 16 contending
// MFMAs (L0's 8 + L1's h1-part 8); the other 8 overlap the tails.
// LDS: h0 par p (p=i&3) @ p*512 ; h1 par q (q=i&1) @ 2048+q*512 ; 3 KiB total.
// Tile layout (512B): (u>>3)*64 + batch*16 + (u&7)*2. A-frag: A row r=h[r>>2]
// -> all 4 C-regs of lane (c,quad) = gate(batch=quad, unit=sw*16+c).
// Steady loop unrolled x4 (compile-time parities). Intervals 0..513.

typedef _Float16 f16x8 __attribute__((ext_vector_type(8)));
typedef float f32x4 __attribute__((ext_vector_type(4)));

#define TSTEPS 512
#define L2E 1.44269504088896340736f

__device__ __forceinline__ float lstm_point(float ai, float af, float ag, float ao,
                                            float& c) {
    // ai,af,ao pre-scaled by -log2e ; ag by +2log2e
    const float p  = __builtin_amdgcn_exp2f(ai);   // e^-i
    const float s_ = __builtin_amdgcn_exp2f(af);   // e^-f
    const float r_ = __builtin_amdgcn_exp2f(ag);   // e^2g
    const float v  = __builtin_amdgcn_exp2f(ao);   // e^-o
    const float m1 = (1.f + p) * (1.f + r_);
    const float R  = __builtin_amdgcn_rcpf(m1 * (1.f + s_));
    const float f  = m1 * R;                       // sigmoid(f)
    const float ig = (r_ - 1.f) * ((1.f + s_) * R);// sigmoid(i)*tanh(g)
    const float cc = __builtin_fmaf(f, c, ig);
    c = cc;
    const float w  = __builtin_amdgcn_exp2f(cc * (2.f * L2E));
    return (w - 1.f) * __builtin_amdgcn_rcpf((1.f + v) * (1.f + w));
}

__global__ __launch_bounds__(512, 2) void lstm2_kernel(
    const float* __restrict__ x,
    const float* __restrict__ W_ih0, const float* __restrict__ W_hh0,
    const float* __restrict__ b_ih0, const float* __restrict__ b_hh0,
    const float* __restrict__ W_ih1, const float* __restrict__ W_hh1,
    const float* __restrict__ b_ih1, const float* __restrict__ b_hh1,
    const float* __restrict__ W_fc,  const float* __restrict__ b_fc,
    float* __restrict__ out)
{
    __shared__ alignas(16) _Float16 H[1536];        // 3 KiB: h0 x4 @0..2047, h1 x2 @2048..3071
    __shared__ alignas(16) float    xl[2][64][4];   // [buf][step][batch]

    const int tid  = (int)threadIdx.x;
    const int lane = tid & 63;
    const int wid  = tid >> 6;          // 0..7
    const int RL   = wid >> 2;          // 0 = layer0 waves, 1 = layer1 waves
    const int sw   = wid & 3;           // sub-wave: units sw*16..sw*16+15
    const int c    = lane & 15;
    const int quad = lane >> 4;         // 0..3 ; lane's batch = quad
    const int j    = (sw << 4) | c;     // lane's hidden unit
    const int b0   = (int)blockIdx.x * 4;

    const int rdOff = quad * 64 + (c >> 2) * 16;     // A-frag: h[c>>2][quad*8+q]
    const int wOff  = (j >> 3) * 64 + quad * 16 + (j & 7) * 2;

    // ---- per-role weight fragments ----
    float biasc0[4], wih0c[4];
    f32x4 cini1[4];
    f16x8 bfA[4][2];              // L0 role: W_hh0, K=64
    f16x8 bfB[4][4];              // L1 role: [W_ih1 | W_hh1], K=128

    if (RL == 0) {
#pragma unroll
        for (int g = 0; g < 4; ++g) {
            const int n = j + 64 * g;
            const float sg = (g == 2) ? (2.0f * L2E) : (-L2E);
            biasc0[g] = sg * (b_ih0[n] + b_hh0[n]);
            wih0c[g]  = sg * W_ih0[n];             // D == 1
#pragma unroll
            for (int kb = 0; kb < 2; ++kb) {
                const float* p = W_hh0 + n * 64 + kb * 32 + quad * 8;
#pragma unroll
                for (int q = 0; q < 8; ++q) bfA[g][kb][q] = (_Float16)(p[q] * sg);
            }
        }
    } else {
#pragma unroll
        for (int g = 0; g < 4; ++g) {
            const int n = j + 64 * g;
            const float sg = (g == 2) ? (2.0f * L2E) : (-L2E);
            const float bb1 = sg * (b_ih1[n] + b_hh1[n]);
            cini1[g][0] = bb1; cini1[g][1] = bb1; cini1[g][2] = bb1; cini1[g][3] = bb1;
#pragma unroll
            for (int kb = 0; kb < 4; ++kb) {
                const int kk = kb * 32 + quad * 8;
                const float* p = (kk < 64) ? (W_ih1 + n * 64 + kk)
                                           : (W_hh1 + n * 64 + (kk - 64));
#pragma unroll
                for (int q = 0; q < 8; ++q) bfB[g][kb][q] = (_Float16)(p[q] * sg);
            }
        }
    }

    // zero-init h1 tiles (h1(-1) read at interval 2 from @2560) + stage x chunk 0
    if (tid < 512) H[1024 + tid] = (_Float16)0.f;    // bytes 2048..3071
    if (tid < 256) xl[0][lane][wid] = x[(b0 + wid) * TSTEPS + lane];
    __syncthreads();

    float cst = 0.f;   // cell state for this lane's point
    char* Hc = (char*)H;
    const char* rdBase = Hc + rdOff;
    char* w00 = Hc + 0    + wOff;     // h0 par0
    char* w01 = Hc + 512  + wOff;     // h0 par1
    char* w02 = Hc + 1024 + wOff;     // h0 par2
    char* w03 = Hc + 1536 + wOff;     // h0 par3
    char* w10 = Hc + 2048 + wOff;     // h1 par0
    char* w11 = Hc + 2560 + wOff;     // h1 par1

    const f32x4 zf4 = {0.f, 0.f, 0.f, 0.f};
    f32x4 accPre[4];                  // L1: pre-accumulated h0(s)-part (+bias)

    // L0 step t: read h0(t-1) @rimm, add pre = x(t)*w_ih + b0, write h0(t) @wp
    auto STEP0 = [&](int rimm, char* wp, int t) {
        const float xq = xl[(t >> 6) & 1][t & 63][quad];
        float pre[4];
#pragma unroll
        for (int g = 0; g < 4; ++g) pre[g] = __builtin_fmaf(xq, wih0c[g], biasc0[g]);
        const f16x8 a0 = *(const f16x8*)(rdBase + rimm);
        const f16x8 a1 = *(const f16x8*)(rdBase + rimm + 256);
        f32x4 acc[4];
        __builtin_amdgcn_s_setprio(1);
#pragma unroll
        for (int g = 0; g < 4; ++g) {
            acc[g] = __builtin_amdgcn_mfma_f32_16x16x32_f16(a0, bfA[g][0], zf4, 0, 0, 0);
            acc[g] = __builtin_amdgcn_mfma_f32_16x16x32_f16(a1, bfA[g][1], acc[g], 0, 0, 0);
        }
        __builtin_amdgcn_s_setprio(0);
        const float hv = lstm_point(acc[0][0] + pre[0], acc[1][0] + pre[1],
                                    acc[2][0] + pre[2], acc[3][0] + pre[3], cst);
        *(_Float16*)wp = (_Float16)hv;
    };

    // L1 finish step s: h0-part already in accPre; read h1(s-1) @h1imm,
    // 8 h1-part MFMAs, tail, write h1(s) @wp.
    auto FIN1 = [&](int h1imm, char* wp) {
        const f16x8 a2 = *(const f16x8*)(rdBase + h1imm);
        const f16x8 a3 = *(const f16x8*)(rdBase + h1imm + 256);
        f32x4 acc[4];
        __builtin_amdgcn_s_setprio(1);
#pragma unroll
        for (int g = 0; g < 4; ++g)
            acc[g] = __builtin_amdgcn_mfma_f32_16x16x32_f16(a2, bfB[g][2], accPre[g], 0, 0, 0);
#pragma unroll
        for (int g = 0; g < 4; ++g)
            acc[g] = __builtin_amdgcn_mfma_f32_16x16x32_f16(a3, bfB[g][3], acc[g], 0, 0, 0);
        __builtin_amdgcn_s_setprio(0);
        const float hv = lstm_point(acc[0][0], acc[1][0], acc[2][0], acc[3][0], cst);
        *(_Float16*)wp = (_Float16)hv;
    };

    // L1 start step s+1: read h0(s+1) @h0imm, 8 h0-part MFMAs -> accPre
    // (runs in the tail window; matrix pipe otherwise idle there)
    auto PRE1 = [&](int h0imm) {
        const f16x8 pa0 = *(const f16x8*)(rdBase + h0imm);
        const f16x8 pa1 = *(const f16x8*)(rdBase + h0imm + 256);
#pragma unroll
        for (int g = 0; g < 4; ++g)
            accPre[g] = __builtin_amdgcn_mfma_f32_16x16x32_f16(pa0, bfB[g][0], cini1[g], 0, 0, 0);
#pragma unroll
        for (int g = 0; g < 4; ++g)
            accPre[g] = __builtin_amdgcn_mfma_f32_16x16x32_f16(pa1, bfB[g][1], accPre[g], 0, 0, 0);
    };

    // ---- interval 0: L0 peel h0(0) -> @0 ----
    if (RL == 0) {
        const float xq = xl[0][0][quad];
        const float hv = lstm_point(__builtin_fmaf(xq, wih0c[0], biasc0[0]),
                                    __builtin_fmaf(xq, wih0c[1], biasc0[1]),
                                    __builtin_fmaf(xq, wih0c[2], biasc0[2]),
                                    __builtin_fmaf(xq, wih0c[3], biasc0[3]), cst);
        *(_Float16*)w00 = (_Float16)hv;
    }
    __syncthreads();

    // ---- interval 1: L0 h0(1) rd@0 wr@512 ; L1 pre-acc h0(0)@0 for s=0 ----
    if (RL == 0) STEP0(0, w01, 1);
    else         PRE1(0);
    __syncthreads();

    // ---- interval 2: L0 h0(2) rd@512 wr@1024 ; L1 fin s=0 (h1(-1)@2560, wr@2048), pre s=1 (h0(1)@512) ----
    if (RL == 0) STEP0(512, w02, 2);
    else { FIN1(2560, w10); PRE1(512); }
    __syncthreads();

    // ---- steady: i = 3,7,...,507 covering intervals i..i+3 (mod 4 = 3,0,1,2) ----
    for (int i = 3; i < 511; i += 4) {
        // i (mod4=3): L0 rd@1024 wr@1536 t=i ; L1 fin s=i-2 (h1@2048 wr@2560), pre s=i-1 (h0@1024)
        if (RL == 0) STEP0(1024, w03, i);
        else { FIN1(2048, w11); PRE1(1024); }
        __syncthreads();
        // i+1 (0): L0 rd@1536 wr@0 t=i+1 (+x staging) ; L1 fin (h1@2560 wr@2048), pre (h0@1536)
        if (RL == 0) {
            const int tB = i + 1;
            if ((tB & 63) == 32 && tB < 448) {
                const int cn = (tB >> 6) + 1;
                xl[cn & 1][lane][wid] = x[(b0 + wid) * TSTEPS + cn * 64 + lane];
            }
            STEP0(1536, w00, tB);
        } else { FIN1(2560, w10); PRE1(1536); }
        __syncthreads();
        // i+2 (1): L0 rd@0 wr@512 t=i+2 ; L1 fin (h1@2048 wr@2560), pre (h0@0)
        if (RL == 0) STEP0(0, w01, i + 2);
        else { FIN1(2048, w11); PRE1(0); }
        __syncthreads();
        // i+3 (2): L0 rd@512 wr@1024 t=i+3 ; L1 fin (h1@2560 wr@2048), pre (h0@512)
        if (RL == 0) STEP0(512, w02, i + 3);
        else { FIN1(2560, w10); PRE1(512); }
        __syncthreads();
    }
    // post-loop: L0 done through t=510; L1 finished through s=508; accPre = h0(509)-part

    // ---- interval 511: L0 h0(511) rd@1024 wr@1536 ; L1 fin s=509 (h1(508)@2048 wr@2560), pre s=510 (h0(510)@1024) ----
    if (RL == 0) STEP0(1024, w03, 511);
    else { FIN1(2048, w11); PRE1(1024); }
    __syncthreads();
    // ---- interval 512: L1 fin s=510 (h1(509)@2560 wr@2048), pre s=511 (h0(511)@1536) ----
    if (RL == 1) { FIN1(2560, w10); PRE1(1536); }
    __syncthreads();
    // ---- interval 513: L1 fin s=511 (h1(510)@2048 wr@2560) ----
    if (RL == 1) FIN1(2048, w11);
    __syncthreads();

    // ---- epilogue: h0(511) @1536 (par3), h1(511) @2560 (par1) ----
    if (tid < 8) {
        const int which = tid >> 2, b = tid & 3;
        const char* hb = Hc + (which ? 2560 : 1536);
        float s = b_fc[0];
        for (int jj = 0; jj < 64; ++jj) {
            const int off = (jj >> 3) * 64 + b * 16 + (jj & 7) * 2;
            s += (float)*(const _Float16*)(hb + off) * W_fc[jj];
        }
        out[which * 1024 + b0 + b] = s;
    }
}

extern "C" void kernel_launch(void* const* d_in, const int* in_sizes, int n_in,
                              void* d_out, int out_size, void* d_ws, size_t ws_size,
                              hipStream_t stream) {
    (void)in_sizes; (void)n_in; (void)d_ws; (void)ws_size; (void)out_size;
    lstm2_kernel<<<256, 512, 0, stream>>>(
        (const float*)d_in[0],
        (const float*)d_in[1], (const float*)d_in[2],
        (const float*)d_in[3], (const float*)d_in[4],
        (const float*)d_in[5], (const float*)d_in[6],
        (const float*)d_in[7], (const float*)d_in[8],
        (const float*)d_in[9], (const float*)d_in[10],
        (float*)d_out);
}

// Round 16
// 255.825 us; speedup vs baseline: 1.0091x; 1.0091x over previous
//
#include <hip/hip_runtime.h>

// 2-layer LSTM, B=1024 T=512 D=1 H=64. 256 blocks x 512 threads (8 waves), MB=4.
// FINAL (R14 revert — session best, 215.8us counter): role-split waves (0-3 =
// L0 step t, 4-7 = L1 step t-2 lag), 1 barrier/interval, batch=quad row-dup
// (A row r = h[r>>2] -> all 4 C-regs = lane's own gate; zero shuffles/cndmask),
// lag-2 pipeline so L1's h0 operand is prefetched into registers one interval
// early (zero post-barrier latency); h1-part MFMAs ordered after the 8
// prefetched-h0 MFMAs so their ds_read latency is covered.
// Ledger at this floor (per SIMD per interval ~1010cyc): MFMA issue ~410
// (irreducible: 24 MFMA = NxK tiles, M-fill free), VALU ~400 (lstm tails,
// algebraically minimal), idle ~210 (barrier+distance-1 ds_read; R8/R12/R15
// attacks all <=0%). LDS: h0 par p (p=i&3) @p*512; h1 par q (q=i&1) @2048+q*512.
// Tile (512B): (u>>3)*64 + batch*16 + (u&7)*2. Steady loop unrolled x4.

typedef _Float16 f16x8 __attribute__((ext_vector_type(8)));
typedef float f32x4 __attribute__((ext_vector_type(4)));

#define TSTEPS 512
#define L2E 1.44269504088896340736f

__device__ __forceinline__ float lstm_point(float ai, float af, float ag, float ao,
                                            float& c) {
    // ai,af,ao pre-scaled by -log2e ; ag by +2log2e
    const float p  = __builtin_amdgcn_exp2f(ai);   // e^-i
    const float s_ = __builtin_amdgcn_exp2f(af);   // e^-f
    const float r_ = __builtin_amdgcn_exp2f(ag);   // e^2g
    const float v  = __builtin_amdgcn_exp2f(ao);   // e^-o
    const float m1 = (1.f + p) * (1.f + r_);
    const float R  = __builtin_amdgcn_rcpf(m1 * (1.f + s_));
    const float f  = m1 * R;                       // sigmoid(f)
    const float ig = (r_ - 1.f) * ((1.f + s_) * R);// sigmoid(i)*tanh(g)
    const float cc = __builtin_fmaf(f, c, ig);
    c = cc;
    const float w  = __builtin_amdgcn_exp2f(cc * (2.f * L2E));
    return (w - 1.f) * __builtin_amdgcn_rcpf((1.f + v) * (1.f + w));
}

__global__ __launch_bounds__(512, 2) void lstm2_kernel(
    const float* __restrict__ x,
    const float* __restrict__ W_ih0, const float* __restrict__ W_hh0,
    const float* __restrict__ b_ih0, const float* __restrict__ b_hh0,
    const float* __restrict__ W_ih1, const float* __restrict__ W_hh1,
    const float* __restrict__ b_ih1, const float* __restrict__ b_hh1,
    const float* __restrict__ W_fc,  const float* __restrict__ b_fc,
    float* __restrict__ out)
{
    __shared__ alignas(16) _Float16 H[1536];        // 3 KiB: h0 x4 @0..2047, h1 x2 @2048..3071
    __shared__ alignas(16) float    xl[2][64][4];   // [buf][step][batch]

    const int tid  = (int)threadIdx.x;
    const int lane = tid & 63;
    const int wid  = tid >> 6;          // 0..7
    const int RL   = wid >> 2;          // 0 = layer0 waves, 1 = layer1 waves
    const int sw   = wid & 3;           // sub-wave: units sw*16..sw*16+15
    const int c    = lane & 15;
    const int quad = lane >> 4;         // 0..3 ; lane's batch = quad
    const int j    = (sw << 4) | c;     // lane's hidden unit
    const int b0   = (int)blockIdx.x * 4;

    const int rdOff = quad * 64 + (c >> 2) * 16;     // A-frag: h[c>>2][quad*8+q]
    const int wOff  = (j >> 3) * 64 + quad * 16 + (j & 7) * 2;

    // ---- per-role weight fragments ----
    float biasc0[4], wih0c[4];
    f32x4 cini1[4];
    f16x8 bfA[4][2];              // L0 role: W_hh0, K=64
    f16x8 bfB[4][4];              // L1 role: [W_ih1 | W_hh1], K=128

    if (RL == 0) {
#pragma unroll
        for (int g = 0; g < 4; ++g) {
            const int n = j + 64 * g;
            const float sg = (g == 2) ? (2.0f * L2E) : (-L2E);
            biasc0[g] = sg * (b_ih0[n] + b_hh0[n]);
            wih0c[g]  = sg * W_ih0[n];             // D == 1
#pragma unroll
            for (int kb = 0; kb < 2; ++kb) {
                const float* p = W_hh0 + n * 64 + kb * 32 + quad * 8;
#pragma unroll
                for (int q = 0; q < 8; ++q) bfA[g][kb][q] = (_Float16)(p[q] * sg);
            }
        }
    } else {
#pragma unroll
        for (int g = 0; g < 4; ++g) {
            const int n = j + 64 * g;
            const float sg = (g == 2) ? (2.0f * L2E) : (-L2E);
            const float bb1 = sg * (b_ih1[n] + b_hh1[n]);
            cini1[g][0] = bb1; cini1[g][1] = bb1; cini1[g][2] = bb1; cini1[g][3] = bb1;
#pragma unroll
            for (int kb = 0; kb < 4; ++kb) {
                const int kk = kb * 32 + quad * 8;
                const float* p = (kk < 64) ? (W_ih1 + n * 64 + kk)
                                           : (W_hh1 + n * 64 + (kk - 64));
#pragma unroll
                for (int q = 0; q < 8; ++q) bfB[g][kb][q] = (_Float16)(p[q] * sg);
            }
        }
    }

    // zero-init h1 tiles (h1(-1) read at interval 2 from @2560) + stage x chunk 0
    if (tid < 512) H[1024 + tid] = (_Float16)0.f;    // bytes 2048..3071
    if (tid < 256) xl[0][lane][wid] = x[(b0 + wid) * TSTEPS + lane];
    __syncthreads();

    float cst = 0.f;   // cell state for this lane's point
    char* Hc = (char*)H;
    const char* rdBase = Hc + rdOff;
    char* w00 = Hc + 0    + wOff;     // h0 par0
    char* w01 = Hc + 512  + wOff;     // h0 par1
    char* w02 = Hc + 1024 + wOff;     // h0 par2
    char* w03 = Hc + 1536 + wOff;     // h0 par3
    char* w10 = Hc + 2048 + wOff;     // h1 par0
    char* w11 = Hc + 2560 + wOff;     // h1 par1

    const f32x4 zf4 = {0.f, 0.f, 0.f, 0.f};
    f16x8 pa0, pa1;                   // L1's prefetched h0(s) frags

    // L0 step t: read h0(t-1) @rimm, add pre = x(t)*w_ih + b0, write h0(t) @wp
    auto STEP0 = [&](int rimm, char* wp, int t) {
        const float xq = xl[(t >> 6) & 1][t & 63][quad];
        float pre[4];
#pragma unroll
        for (int g = 0; g < 4; ++g) pre[g] = __builtin_fmaf(xq, wih0c[g], biasc0[g]);
        const f16x8 a0 = *(const f16x8*)(rdBase + rimm);
        const f16x8 a1 = *(const f16x8*)(rdBase + rimm + 256);
        f32x4 acc[4];
        __builtin_amdgcn_s_setprio(1);
#pragma unroll
        for (int g = 0; g < 4; ++g) {
            acc[g] = __builtin_amdgcn_mfma_f32_16x16x32_f16(a0, bfA[g][0], zf4, 0, 0, 0);
            acc[g] = __builtin_amdgcn_mfma_f32_16x16x32_f16(a1, bfA[g][1], acc[g], 0, 0, 0);
        }
        __builtin_amdgcn_s_setprio(0);
        const float hv = lstm_point(acc[0][0] + pre[0], acc[1][0] + pre[1],
                                    acc[2][0] + pre[2], acc[3][0] + pre[3], cst);
        *(_Float16*)wp = (_Float16)hv;
    };

    // L1 step s: h0(s) in pa0/pa1 (prefetched); read h1(s-1) @h1imm; write @wp.
    // h0-part MFMAs first (no wait) cover the h1 ds_read latency.
    auto STEP1 = [&](int h1imm, char* wp) {
        const f16x8 a2 = *(const f16x8*)(rdBase + h1imm);
        const f16x8 a3 = *(const f16x8*)(rdBase + h1imm + 256);
        f32x4 acc[4];
        __builtin_amdgcn_s_setprio(1);
#pragma unroll
        for (int g = 0; g < 4; ++g)
            acc[g] = __builtin_amdgcn_mfma_f32_16x16x32_f16(pa0, bfB[g][0], cini1[g], 0, 0, 0);
#pragma unroll
        for (int g = 0; g < 4; ++g)
            acc[g] = __builtin_amdgcn_mfma_f32_16x16x32_f16(pa1, bfB[g][1], acc[g], 0, 0, 0);
#pragma unroll
        for (int g = 0; g < 4; ++g)
            acc[g] = __builtin_amdgcn_mfma_f32_16x16x32_f16(a2, bfB[g][2], acc[g], 0, 0, 0);
#pragma unroll
        for (int g = 0; g < 4; ++g)
            acc[g] = __builtin_amdgcn_mfma_f32_16x16x32_f16(a3, bfB[g][3], acc[g], 0, 0, 0);
        __builtin_amdgcn_s_setprio(0);
        const float hv = lstm_point(acc[0][0], acc[1][0], acc[2][0], acc[3][0], cst);
        *(_Float16*)wp = (_Float16)hv;
    };

    auto PF = [&](int h0imm) {        // prefetch next interval's h0(s) frags
        pa0 = *(const f16x8*)(rdBase + h0imm);
        pa1 = *(const f16x8*)(rdBase + h0imm + 256);
    };

    // ---- interval 0: L0 peel h0(0) -> @0 ----
    if (RL == 0) {
        const float xq = xl[0][0][quad];
        const float hv = lstm_point(__builtin_fmaf(xq, wih0c[0], biasc0[0]),
                                    __builtin_fmaf(xq, wih0c[1], biasc0[1]),
                                    __builtin_fmaf(xq, wih0c[2], biasc0[2]),
                                    __builtin_fmaf(xq, wih0c[3], biasc0[3]), cst);
        *(_Float16*)w00 = (_Float16)hv;
    }
    __syncthreads();

    // ---- interval 1: L0 h0(1) rd@0 wr@512 ; L1 prefetch h0(0)@0 ----
    if (RL == 0) STEP0(0, w01, 1);
    else         PF(0);
    __syncthreads();

    // ---- interval 2: L0 h0(2) rd@512 wr@1024 ; L1 h1(0): rd h1(-1)@2560, wr@2048; PF h0(1)@512 ----
    if (RL == 0) STEP0(512, w02, 2);
    else { STEP1(2560, w10); PF(512); }
    __syncthreads();

    // ---- steady: i = 3,7,...,507 covering intervals i..i+3 (mod 4 = 3,0,1,2) ----
    for (int i = 3; i < 511; i += 4) {
        // i=3 (mod4): L0 rd@1024 wr@1536 t=i ; L1 s=i-2: rd h1@2048 wr@2560; PF@1024
        if (RL == 0) STEP0(1024, w03, i);
        else { STEP1(2048, w11); PF(1024); }
        __syncthreads();
        // i+1=0: L0 rd@1536 wr@0 t=i+1 (+x staging) ; L1 rd h1@2560 wr@2048; PF@1536
        if (RL == 0) {
            const int tB = i + 1;
            if ((tB & 63) == 32 && tB < 448) {
                const int cn = (tB >> 6) + 1;
                xl[cn & 1][lane][wid] = x[(b0 + wid) * TSTEPS + cn * 64 + lane];
            }
            STEP0(1536, w00, tB);
        } else { STEP1(2560, w10); PF(1536); }
        __syncthreads();
        // i+2=1: L0 rd@0 wr@512 t=i+2 ; L1 rd h1@2048 wr@2560; PF@0
        if (RL == 0) STEP0(0, w01, i + 2);
        else { STEP1(2048, w11); PF(0); }
        __syncthreads();
        // i+3=2: L0 rd@512 wr@1024 t=i+3 ; L1 rd h1@2560 wr@2048; PF@512
        if (RL == 0) STEP0(512, w02, i + 3);
        else { STEP1(2560, w10); PF(512); }
        __syncthreads();
    }
    // post-loop: L0 done through t=510; L1 done through s=508; pa=h0(509)@512

    // ---- interval 511: L0 h0(511) rd@1024 wr@1536 ; L1 h1(509): rd h1(508)@2048 wr@2560; PF h0(510)@1024 ----
    if (RL == 0) STEP0(1024, w03, 511);
    else { STEP1(2048, w11); PF(1024); }
    __syncthreads();
    // ---- interval 512: L1 h1(510): rd h1(509)@2560 wr@2048; PF h0(511)@1536 ----
    if (RL == 1) { STEP1(2560, w10); PF(1536); }
    __syncthreads();
    // ---- interval 513: L1 h1(511): rd h1(510)@2048 wr@2560 ----
    if (RL == 1) STEP1(2048, w11);
    __syncthreads();

    // ---- epilogue: h0(511) @1536 (par3), h1(511) @2560 (par1) ----
    if (tid < 8) {
        const int which = tid >> 2, b = tid & 3;
        const char* hb = Hc + (which ? 2560 : 1536);
        float s = b_fc[0];
        for (int jj = 0; jj < 64; ++jj) {
            const int off = (jj >> 3) * 64 + b * 16 + (jj & 7) * 2;
            s += (float)*(const _Float16*)(hb + off) * W_fc[jj];
        }
        out[which * 1024 + b0 + b] = s;
    }
}

extern "C" void kernel_launch(void* const* d_in, const int* in_sizes, int n_in,
                              void* d_out, int out_size, void* d_ws, size_t ws_size,
                              hipStream_t stream) {
    (void)in_sizes; (void)n_in; (void)d_ws; (void)ws_size; (void)out_size;
    lstm2_kernel<<<256, 512, 0, stream>>>(
        (const float*)d_in[0],
        (const float*)d_in[1], (const float*)d_in[2],
        (const float*)d_in[3], (const float*)d_in[4],
        (const float*)d_in[5], (const float*)d_in[6],
        (const float*)d_in[7], (const float*)d_in[8],
        (const float*)d_in[9], (const float*)d_in[10],
        (float*)d_out);
}